// Round 8
// baseline (503.628 us; speedup 1.0000x reference)
//
#include <hip/hip_runtime.h>
#include <hip/hip_bf16.h>
#include <string.h>

typedef unsigned short u16;
typedef unsigned int   u32;
using short8  = __attribute__((ext_vector_type(8))) short;
using float4v = __attribute__((ext_vector_type(4))) float;

#define DEV static __device__ __forceinline__

DEV u16 f2bf(float f) {
  union { float f; u32 u; } v; v.f = f;
  u32 u = v.u;
  return (u16)((u + 0x7fffu + ((u >> 16) & 1u)) >> 16);   // RNE
}
DEV float bf2f(u16 b) {
  union { u32 u; float f; } v; v.u = ((u32)b) << 16;
  return v.f;
}
DEV void gload16(const void* g, void* lds) {
  __builtin_amdgcn_global_load_lds((const __attribute__((address_space(1))) void*)g,
                                   (__attribute__((address_space(3))) void*)lds, 16, 0, 0);
}
DEV float4v mfma16(short8 a, short8 b, float4v c) {
  return __builtin_amdgcn_mfma_f32_16x16x32_bf16(a, b, c, 0, 0, 0);
}

// ---------------- problem constants ----------------
#define SCALE_F 0.07216878364870323f        // (3*64)^-0.5
#define KSQS_F  0.10412730065142986f        // SCALE * log2(e)
#define C2_F    0.20825460130285973f        // 2 * SCALE * log2(e)
#define THR_F   11.541560327111707f         // 8 * log2(e)

// ---------------- workspace layout (byte offsets) ----------------
// Peak byte-identical to the proven R4 layout (<= 90,570,752 B).
#define OFF_XH   0ull
#define OFF_XL   6291456ull
#define OFF_AO1  0ull                        // partial 0; aliases X (dead after qkv_gemm)
#define OFF_WH   12582912ull                 // W region; dead after GEMMs -> reused as MS
#define OFF_WL   13369344ull
#define OFF_WOH  14155776ull
#define OFF_MS3  12582912ull                 // f32 [3][16][2048][2] = 786,432 B (in dead W region)
#define OFF_QKVH 14417920ull
#define OFF_QKVL 39583744ull
#define OFF_VT   64749568ull
#define OFF_KSQ  77332480ull                 // f32 [16][2048] pre-scaled
#define OFF_AO2  77987840ull                 // partial 1 (bf16 [3][4096][512])
// partial 2 aliases d_out (12,582,912 B, overwritten later by out_gemm)

// ================= kernel 1: split inputs into bf16 hi/lo =================
__global__ __launch_bounds__(256) void prep_kernel(
    const float* __restrict__ x, const float* __restrict__ wq,
    const float* __restrict__ wkv, const float* __restrict__ wout,
    u16* __restrict__ XH, u16* __restrict__ XL,
    u16* __restrict__ WH, u16* __restrict__ WL, u16* __restrict__ WOH) {
  int t = blockIdx.x * 256 + threadIdx.x;
  if (t < 1048576) {                       // per (bn,i): coalesced float3 read
    const float* xp = x + t * 3;
    float f0 = xp[0], f1 = xp[1], f2 = xp[2];
#pragma unroll
    for (int c = 0; c < 3; ++c) {
      float f = (c == 0) ? f0 : (c == 1 ? f1 : f2);
      u16 h = f2bf(f);
      XH[c * 1048576 + t] = h;
      XL[c * 1048576 + t] = f2bf(f - bf2f(h));
    }
  } else if (t < 1048576 + 393216) {       // w_q / w_kv rows, K contiguous
    int wi = t - 1048576;
    int o = wi >> 8, i = wi & 255;
    float f = (o < 512) ? wq[o * 256 + i] : wkv[(o - 512) * 256 + i];
    u16 h = f2bf(f);
    WH[wi] = h;
    WL[wi] = f2bf(f - bf2f(h));
  } else if (t < 1048576 + 393216 + 131072) {
    int wi = t - 1048576 - 393216;
    WOH[wi] = f2bf(wout[wi]);
  }
}

// ================= kernel 2: QKV projection GEMM (bf16x2) =================
__global__ __launch_bounds__(256) void qkv_gemm(
    const u16* __restrict__ XH, const u16* __restrict__ XL,
    const u16* __restrict__ WH, const u16* __restrict__ WL,
    u16* __restrict__ QKVH, u16* __restrict__ QKVL, u16* __restrict__ VT) {
  __shared__ u16 smem[16384];
  int m0 = blockIdx.x * 128;
  int n0 = blockIdx.y * 128;
  bool isV = (n0 >= 1024);
  int tid = threadIdx.x, lane = tid & 63, wave = tid >> 6;
  int la = lane & 15, qa = lane >> 4;
  int wm = wave >> 1, wn = wave & 1;

  float4v acc[4][4];
#pragma unroll
  for (int i = 0; i < 4; ++i)
#pragma unroll
    for (int j = 0; j < 4; ++j) acc[i][j] = (float4v){0.f, 0.f, 0.f, 0.f};

  for (int k0 = 0; k0 < 256; k0 += 32) {
    __syncthreads();
#pragma unroll
    for (int it = 0; it < 8; ++it) {
      int cb = it * 256 + wave * 64;
      int n = cb + lane;
      int region = n >> 9;
      if (isV && (region & 1)) continue;
      int nn = n & 511;
      int row = nn >> 2, p = nn & 3;
      int q = p ^ ((row >> 1) & 3);
      const u16* src;
      if (region == 0)      src = XH + (m0 + row) * 256 + k0 + q * 8;
      else if (region == 1) src = XL + (m0 + row) * 256 + k0 + q * 8;
      else if (region == 2) src = WH + (n0 + row) * 256 + k0 + q * 8;
      else                  src = WL + (n0 + row) * 256 + k0 + q * 8;
      gload16(src, smem + cb * 8);
    }
    __syncthreads();

    short8 ah[4], al[4];
#pragma unroll
    for (int mi = 0; mi < 4; ++mi) {
      int row = wm * 64 + mi * 16 + la;
      int off = row * 32 + ((qa ^ ((row >> 1) & 3)) * 8);
      ah[mi] = *(const short8*)(smem + off);
      if (!isV) al[mi] = *(const short8*)(smem + 4096 + off);
    }
#pragma unroll
    for (int ni = 0; ni < 4; ++ni) {
      int row = wn * 64 + ni * 16 + la;
      int off = row * 32 + ((qa ^ ((row >> 1) & 3)) * 8);
      short8 bh = *(const short8*)(smem + 8192 + off);
      if (!isV) {
        short8 bl = *(const short8*)(smem + 12288 + off);
#pragma unroll
        for (int mi = 0; mi < 4; ++mi) {
          acc[mi][ni] = mfma16(ah[mi], bh, acc[mi][ni]);
          acc[mi][ni] = mfma16(ah[mi], bl, acc[mi][ni]);
          acc[mi][ni] = mfma16(al[mi], bh, acc[mi][ni]);
        }
      } else {
#pragma unroll
        for (int mi = 0; mi < 4; ++mi) acc[mi][ni] = mfma16(ah[mi], bh, acc[mi][ni]);
      }
    }
  }

#pragma unroll
  for (int mi = 0; mi < 4; ++mi)
#pragma unroll
    for (int ni = 0; ni < 4; ++ni) {
      int n = n0 + wn * 64 + ni * 16 + la;
      int mbase = m0 + wm * 64 + mi * 16 + qa * 4;
#pragma unroll
      for (int r = 0; r < 4; ++r) {
        int m = mbase + r;
        float v = acc[mi][ni][r];
        if (!isV) {
          u16 h = f2bf(v);
          QKVH[m * 1024 + n] = h;
          QKVL[m * 1024 + n] = f2bf(v - bf2f(h));
        } else {
          int c = m >> 12, bn = m & 4095;
          int bb = bn >> 11, j = bn & 2047;
          int hd = n - 1024;
          int hh = hd >> 6, d = hd & 63;
          VT[((bb * 8 + hh) * 192 + (c * 64 + d)) * 2048 + j] = f2bf(v);
        }
      }
    }
}

// ================= kernel 3: KSQ2[bh][j] = (sum k^2) * SCALE*log2e =========
__global__ __launch_bounds__(512) void ksq_kernel(
    const u16* __restrict__ QKVH, const u16* __restrict__ QKVL, float* __restrict__ KSQ2) {
  int bn = blockIdx.x;
  int t = threadIdx.x;
  float s = 0.f;
#pragma unroll
  for (int c = 0; c < 3; ++c) {
    int off = (c * 4096 + bn) * 1024 + 512 + t;
    float v = bf2f(QKVH[off]) + bf2f(QKVL[off]);
    s += v * v;
  }
#pragma unroll
  for (int o = 1; o < 64; o <<= 1) s += __shfl_xor(s, o);
  if ((t & 63) == 0) {
    int h = t >> 6;
    int b = bn >> 11, j = bn & 2047;
    KSQ2[(b * 8 + h) * 2048 + j] = s * KSQS_F;
  }
}

// ================= kernel 4: flash attention, 256-thr / 3 blocks per CU ===
// grid 1536 (16 bh x 32 qb x 3 j-thirds), 4 waves x 16 Q rows (QB=64),
// KVB=16, K+V double-buffered. LDS: per buf {Kh[16][192]@0 Kl@3072 V[192][16]@6144}
// = 9216 u16; x2 = 18432 u16; sP @18432 (1024 u16/wave) -> 45,056 B total.
// 3 blocks/CU requires total regs <= 170 -> __launch_bounds__(256,3).
// PV uses 16x16x32 with j 16..31 as A-side zeros (sP cols 16..31 zeroed once;
// qa>=2 V reads duplicate qa&1 data so 0 x finite = 0).
__global__ __launch_bounds__(256, 3) void attn_kernel(
    const u16* __restrict__ QKVH, const u16* __restrict__ QKVL,
    const u16* __restrict__ VT, const float* __restrict__ KSQ2,
    u16* __restrict__ P0, u16* __restrict__ P1, u16* __restrict__ P2,
    float* __restrict__ MS) {
  __shared__ u16 smem[22528];
  const int BUFU = 9216;
  int wgid = blockIdx.x;
  int xcd = wgid & 7, slot = wgid >> 3;         // 192 slots per XCD
  int bh = xcd * 2 + (slot & 1);                // XCD owns bh pair -> K/V L2-resident
  int rem = slot >> 1;                          // 0..95
  int qb = rem & 31, third = rem >> 5;          // 0..31, 0..2
  int b = bh >> 3, h = bh & 7;
  int jbase = third * 688;
  int niter = (third == 2) ? 42 : 43;           // 688/688/672 j's
  int tid = threadIdx.x, wave = tid >> 6, lane = tid & 63;
  int la = lane & 15, qa = lane >> 4;

  // Q fragments in registers (16 rows per wave)
  short8 qh[6], ql[6];
  int irow = qb * 64 + wave * 16 + la;
#pragma unroll
  for (int kk = 0; kk < 6; ++kk) {
    int kap = kk * 32 + qa * 8;
    int c = kap >> 6, d0 = kap & 63;
    int off = (c * 4096 + b * 2048 + irow) * 1024 + h * 64 + d0;
    qh[kk] = *(const short8*)(QKVH + off);
    ql[kk] = *(const short8*)(QKVL + off);
  }
  float4v O[12];
#pragma unroll
  for (int i = 0; i < 12; ++i) O[i] = (float4v){0.f, 0.f, 0.f, 0.f};
  float mr[4] = {-1e30f, -1e30f, -1e30f, -1e30f};
  float ssum[4] = {0.f, 0.f, 0.f, 0.f};          // lane-partial over la
  const float* ksqp = KSQ2 + bh * 2048 + jbase;
  u16* sP = smem + 18432 + wave * 1024;          // rows stride 40 u16 (80 B)

  // zero sP cols 16..31 once (A-side zeros for the padded PV half)
  if (qa >= 2) *(short8*)(sP + la * 40 + qa * 8) = (short8){0, 0, 0, 0, 0, 0, 0, 0};

  // ---- staging offsets: K 384 chunks (hi+lo share), V 384 chunks ----
  bool x2 = tid < 128;
  u32 ofsK0, ofsK1 = 0, ofsV0, ofsV1 = 0;
  {
    int g = tid, j = g / 24, p = g - j * 24;
    int q = (p & ~7) | ((p ^ j) & 7);
    ofsK0 = (u32)(((q >> 3) * 4096 + b * 2048 + jbase + j) * 1024 + 512 + h * 64 + (q & 7) * 8);
  }
  if (x2) {
    int g = 256 + tid, j = g / 24, p = g - j * 24;
    int q = (p & ~7) | ((p ^ j) & 7);
    ofsK1 = (u32)(((q >> 3) * 4096 + b * 2048 + jbase + j) * 1024 + 512 + h * 64 + (q & 7) * 8);
  }
  {
    int g = tid, f = g >> 1, c = g & 1;
    ofsV0 = (u32)(f * 2048 + jbase + (c ^ ((f >> 2) & 1)) * 8);
  }
  if (x2) {
    int g = 256 + tid, f = g >> 1, c = g & 1;
    ofsV1 = (u32)(f * 2048 + jbase + (c ^ ((f >> 2) & 1)) * 8);
  }
  const u16* VTb = VT + (size_t)(b * 8 + h) * 192 * 2048;

  auto STAGE = [&](int bo) {
    gload16(QKVH + ofsK0, smem + bo + tid * 8);
    gload16(QKVL + ofsK0, smem + bo + 3072 + tid * 8);
    gload16(VTb + ofsV0, smem + bo + 6144 + tid * 8);
    if (x2) {
      gload16(QKVH + ofsK1, smem + bo + 2048 + tid * 8);
      gload16(QKVL + ofsK1, smem + bo + 3072 + 2048 + tid * 8);
      gload16(VTb + ofsV1, smem + bo + 6144 + 2048 + tid * 8);
      ofsK1 += 16384; ofsV1 += 16;
    }
    ofsK0 += 16384; ofsV0 += 16;
  };

  STAGE(0);
  __syncthreads();      // vmcnt(0): tile 0 ready

  int bo = 0;
  for (int t = 0; t < niter; ++t) {
    float kq = ksqp[t * 16 + la];
    if (t + 1 < niter) STAGE(bo ^ BUFU);

    // ---- QK^T (3-term bf16x2), 16 rows x 16 j ----
    float4v S = (float4v){0.f, 0.f, 0.f, 0.f};
    __builtin_amdgcn_s_setprio(1);
#pragma unroll
    for (int kk = 0; kk < 6; ++kk) {
      int lc = kk * 4 + qa;
      int ch = (lc & ~7) | ((lc ^ la) & 7);
      int off = bo + la * 192 + ch * 8;
      short8 kh = *(const short8*)(smem + off);
      short8 kl = *(const short8*)(smem + 3072 + off);
      S = mfma16(qh[kk], kh, S);
      S = mfma16(qh[kk], kl, S);
      S = mfma16(ql[kk], kh, S);
    }
    __builtin_amdgcn_s_setprio(0);

    // ---- online softmax in log2 domain ----
    float Lh[4];
#pragma unroll
    for (int r = 0; r < 4; ++r) Lh[r] = __builtin_fmaf(S[r], C2_F, -kq);
    float worst = fmaxf(fmaxf(Lh[0] - mr[0], Lh[1] - mr[1]),
                        fmaxf(Lh[2] - mr[2], Lh[3] - mr[3]));
    float p[4];
    if (__all(worst <= THR_F)) {
#pragma unroll
      for (int r = 0; r < 4; ++r) {
        p[r] = __builtin_exp2f(Lh[r] - mr[r]);
        ssum[r] += p[r];
      }
    } else {
#pragma unroll
      for (int r = 0; r < 4; ++r) {
        float rm = Lh[r];
#pragma unroll
        for (int o = 1; o < 16; o <<= 1) rm = fmaxf(rm, __shfl_xor(rm, o));
        float mn = fmaxf(mr[r], rm);
        float alpha = __builtin_exp2f(mr[r] - mn);
        mr[r] = mn;
        p[r] = __builtin_exp2f(Lh[r] - mn);
        ssum[r] = ssum[r] * alpha + p[r];
#pragma unroll
        for (int nf2 = 0; nf2 < 12; ++nf2) O[nf2][r] *= alpha;
      }
    }

    // ---- P -> per-wave LDS (cols 0..15), read back as A-frag ----
#pragma unroll
    for (int r = 0; r < 4; r += 2) {
      __hip_bfloat162 b2 = __float22bfloat162_rn(float2{p[r], p[r + 1]});
      u32 pk; memcpy(&pk, &b2, 4);
      sP[(qa * 4 + r) * 40 + la] = (u16)pk;
      sP[(qa * 4 + r + 1) * 40 + la] = (u16)(pk >> 16);
    }
    short8 pa = *(const short8*)(sP + la * 40 + qa * 8);   // qa>=2: zeros

    // ---- PV (j 16..31 padded: qa>=2 duplicates qa&1 V, nulled by pa=0) ----
    __builtin_amdgcn_s_setprio(1);
#pragma unroll
    for (int nf = 0; nf < 12; ++nf) {
      int f = nf * 16 + la;
      int c = (qa & 1) ^ ((f >> 2) & 1);
      int off = bo + 6144 + f * 16 + c * 8;
      short8 vf = *(const short8*)(smem + off);
      O[nf] = mfma16(pa, vf, O[nf]);
    }
    __builtin_amdgcn_s_setprio(0);

    __syncthreads();   // vmcnt(0)+lgkm: next tile staged; swap
    bo ^= BUFU;
  }

  // epilogue: reduce lane-partial ssum over 16 col-lanes, write partial
  float inv[4];
#pragma unroll
  for (int r = 0; r < 4; ++r) {
    float s = ssum[r];
#pragma unroll
    for (int o = 1; o < 16; o <<= 1) s += __shfl_xor(s, o);
    ssum[r] = s;
    inv[r] = 1.0f / s;
  }
  u16* AOp = (third == 0) ? P0 : (third == 1) ? P1 : P2;
#pragma unroll
  for (int nf = 0; nf < 12; ++nf) {
    int f = nf * 16 + la;
    int c = f >> 6, d = f & 63;
#pragma unroll
    for (int r = 0; r < 4; ++r) {
      int ig = qb * 64 + wave * 16 + qa * 4 + r;
      AOp[(c * 4096 + b * 2048 + ig) * 512 + h * 64 + d] = f2bf(O[nf][r] * inv[r]);
    }
  }
  if (la == 0) {
#pragma unroll
    for (int r = 0; r < 4; ++r) {
      int ig = qb * 64 + wave * 16 + qa * 4 + r;
      float* msp = MS + (size_t)((third * 16 + bh) * 2048 + ig) * 2;
      msp[0] = mr[r];
      msp[1] = ssum[r];
    }
  }
}

// ================= kernel 4b: merge the three KV thirds ===================
__global__ __launch_bounds__(256) void merge_kernel(
    u16* __restrict__ P0, const u16* __restrict__ P1, const u16* __restrict__ P2,
    const float* __restrict__ MS) {
  int t = blockIdx.x * 256 + threadIdx.x;
  int base = t * 8;
  int rowg = base >> 9;
  int h = (base & 511) >> 6;
  int bn = rowg & 4095;
  int bb = bn >> 11, ig = bn & 2047;
  int bh = bb * 8 + h;
  const float* m0p = MS + (size_t)(bh * 2048 + ig) * 2;
  const float* m1p = m0p + 16 * 2048 * 2;
  const float* m2p = m1p + 16 * 2048 * 2;
  float m0 = m0p[0], s0 = m0p[1];
  float m1 = m1p[0], s1 = m1p[1];
  float m2 = m2p[0], s2 = m2p[1];
  float m = fmaxf(m0, fmaxf(m1, m2));
  float a0 = __builtin_exp2f(m0 - m) * s0;
  float a1 = __builtin_exp2f(m1 - m) * s1;
  float a2 = __builtin_exp2f(m2 - m) * s2;
  float inv = 1.0f / (a0 + a1 + a2);
  float w0 = a0 * inv, w1 = a1 * inv, w2 = a2 * inv;
  short8 o0 = *(const short8*)(P0 + base);
  short8 o1 = *(const short8*)(P1 + base);
  short8 o2 = *(const short8*)(P2 + base);
  short8 out;
#pragma unroll
  for (int j = 0; j < 8; ++j)
    out[j] = (short)f2bf(w0 * bf2f((u16)o0[j]) + w1 * bf2f((u16)o1[j]) + w2 * bf2f((u16)o2[j]));
  *(short8*)(P0 + base) = out;
}

// ================= kernel 5: final projection GEMM ========================
__global__ __launch_bounds__(256) void out_gemm(
    const u16* __restrict__ AO, const u16* __restrict__ WOH, float* __restrict__ OUT) {
  __shared__ u16 smem[8192];
  int m0 = blockIdx.x * 128, n0 = blockIdx.y * 128;
  int tid = threadIdx.x, lane = tid & 63, wave = tid >> 6;
  int la = lane & 15, qa = lane >> 4;
  int wm = wave >> 1, wn = wave & 1;

  float4v acc[4][4];
#pragma unroll
  for (int i = 0; i < 4; ++i)
#pragma unroll
    for (int j = 0; j < 4; ++j) acc[i][j] = (float4v){0.f, 0.f, 0.f, 0.f};

  for (int k0 = 0; k0 < 512; k0 += 32) {
    __syncthreads();
#pragma unroll
    for (int it = 0; it < 4; ++it) {
      int cb = it * 256 + wave * 64;
      int n = cb + lane;
      int region = n >> 9;
      int nn = n & 511;
      int row = nn >> 2, p = nn & 3;
      int q = p ^ ((row >> 1) & 3);
      const u16* src = (region == 0) ? AO + (m0 + row) * 512 + k0 + q * 8
                                     : WOH + (n0 + row) * 512 + k0 + q * 8;
      gload16(src, smem + cb * 8);
    }
    __syncthreads();

    short8 ah[4];
#pragma unroll
    for (int mi = 0; mi < 4; ++mi) {
      int row = wm * 64 + mi * 16 + la;
      int off = row * 32 + ((qa ^ ((row >> 1) & 3)) * 8);
      ah[mi] = *(const short8*)(smem + off);
    }
#pragma unroll
    for (int ni = 0; ni < 4; ++ni) {
      int row = wn * 64 + ni * 16 + la;
      int off = row * 32 + ((qa ^ ((row >> 1) & 3)) * 8);
      short8 bhf = *(const short8*)(smem + 4096 + off);
#pragma unroll
      for (int mi = 0; mi < 4; ++mi) acc[mi][ni] = mfma16(ah[mi], bhf, acc[mi][ni]);
    }
  }

#pragma unroll
  for (int mi = 0; mi < 4; ++mi)
#pragma unroll
    for (int ni = 0; ni < 4; ++ni) {
      int n = n0 + wn * 64 + ni * 16 + la;
      int mbase = m0 + wm * 64 + mi * 16 + qa * 4;
#pragma unroll
      for (int r = 0; r < 4; ++r) {
        int m = mbase + r;
        int c = m >> 12, bn = m & 4095;
        OUT[bn * 768 + n * 3 + c] = acc[mi][ni][r];
      }
    }
}

// ================= launch =================================================
extern "C" void kernel_launch(void* const* d_in, const int* in_sizes, int n_in,
                              void* d_out, int out_size, void* d_ws, size_t ws_size,
                              hipStream_t stream) {
  const float* x    = (const float*)d_in[0];
  const float* wq   = (const float*)d_in[2];
  const float* wkv  = (const float*)d_in[3];
  const float* wout = (const float*)d_in[4];

  char* ws = (char*)d_ws;
  u16*  XH   = (u16*)(ws + OFF_XH);
  u16*  XL   = (u16*)(ws + OFF_XL);
  u16*  AO1  = (u16*)(ws + OFF_AO1);
  u16*  WH   = (u16*)(ws + OFF_WH);
  u16*  WL   = (u16*)(ws + OFF_WL);
  u16*  WOH  = (u16*)(ws + OFF_WOH);
  u16*  QKVH = (u16*)(ws + OFF_QKVH);
  u16*  QKVL = (u16*)(ws + OFF_QKVL);
  u16*  VT   = (u16*)(ws + OFF_VT);
  float* KSQ2 = (float*)(ws + OFF_KSQ);
  float* MS3  = (float*)(ws + OFF_MS3);
  u16*  P1   = (u16*)(ws + OFF_AO2);
  u16*  P2   = (u16*)d_out;                 // scratch until out_gemm overwrites

  prep_kernel<<<6144, 256, 0, stream>>>(x, wq, wkv, wout, XH, XL, WH, WL, WOH);
  qkv_gemm<<<dim3(96, 12), 256, 0, stream>>>(XH, XL, WH, WL, QKVH, QKVL, VT);
  ksq_kernel<<<4096, 512, 0, stream>>>(QKVH, QKVL, KSQ2);
  attn_kernel<<<1536, 256, 0, stream>>>(QKVH, QKVL, VT, KSQ2, AO1, P1, P2, MS3);
  merge_kernel<<<3072, 256, 0, stream>>>(AO1, P1, P2, MS3);
  out_gemm<<<dim3(96, 2), 256, 0, stream>>>(AO1, WOH, (float*)d_out);
}